// Round 2
// baseline (1218.598 us; speedup 1.0000x reference)
//
#include <hip/hip_runtime.h>

// ---------- helpers ----------
__device__ __forceinline__ float bf2f(unsigned short u) {
  union { unsigned int i; float f; } v; v.i = ((unsigned int)u) << 16; return v.f;
}
__device__ __forceinline__ unsigned short f2bf(float f) {
  union { float f; unsigned int i; } v; v.f = f;
  return (unsigned short)((v.i + 0x7fffu + ((v.i >> 16) & 1u)) >> 16);
}
__device__ __forceinline__ float ftanh(float x) {
  float e = __expf(2.f * x);
  return 1.f - 2.f / (e + 1.f);
}

// ---------- weight permutation ----------
// W0p bf16 [loc(400)][co(32)][k(60)]; k = l*18 + c*3 + r (k>=54 zero)
// W1p[(loc*64+o)*128 + (k*2+l)*32 + c] = W1[(loc*64+o)*128 + c*4 + k*2+l]
// W2p[(loc*128+o)*1600 + (k*5+l)*64 + c] = W2[(loc*128+o)*1600 + c*25 + k*5+l]
__global__ __launch_bounds__(256) void k_permute(const float* __restrict__ W0,
                                                 const float* __restrict__ W1,
                                                 const float* __restrict__ W2,
                                                 unsigned short* __restrict__ W0p,
                                                 float* __restrict__ W1p,
                                                 float* __restrict__ W2p) {
  int idx = blockIdx.x * 256 + threadIdx.x;
  if (idx < 768000) {
    int loc = idx / 1920, f = idx - loc * 1920;
    int co = f / 60, k = f - co * 60;
    unsigned short v = 0;
    if (k < 54) {
      int l = k / 18, rem = k - l * 18;
      int c = rem / 3, r = rem - c * 3;
      v = f2bf(W0[loc * 1728 + co * 54 + c * 9 + r * 3 + l]);
    }
    W0p[idx] = v;
  } else if (idx < 768000 + 819200) {
    int j = idx - 768000;
    int row = j >> 7, f = j & 127;
    int kl = f >> 5, c = f & 31;
    W1p[j] = W1[(row << 7) + (c << 2) + kl];
  } else {
    int j = idx - 1587200;
    int row = j / 1600;
    int f = j - row * 1600;
    int kl5 = f >> 6, c = f & 63;
    W2p[j] = W2[row * 1600 + c * 25 + kl5];
  }
}

// ---------- layer 0 v2: row-slab staging + 20 per-j mini-GEMMs ----------
// grid (256 batch-tiles of 16, 20 i-rows), block 128.
// sX bf16 [16 b][20 j][k pad 56], b-stride 1132 us (566 dw); patches disjoint (stride==kernel).
// sW bf16 [4 j][32 co][k pad 60], j-stride 1928 us (964 dw).
// h0 layout: [b][loc1(10x10)][kl(2x2)][c(32)]
__global__ __launch_bounds__(128) void k_l0(const float* __restrict__ x,
                                            const unsigned short* __restrict__ W0p,
                                            const float* __restrict__ B0,
                                            unsigned short* __restrict__ h0) {
  const int t  = threadIdx.x;
  const int b0 = blockIdx.x << 4;
  const int i  = blockIdx.y;

  __shared__ __align__(16) unsigned short sX[16 * 1132];   // 36224 B
  __shared__ __align__(16) unsigned short sW[4 * 1928];    // 15424 B

  // ---- stage x slab: [16 b][6 c][3 r][60 col] coalesced float4, transpose to [b][j][k]
  for (int e = t; e < 4320; e += 128) {
    int b = e / 270, rem = e - b * 270;
    int cr = rem / 15, q = rem - cr * 15;          // cr = c*3+r, cols 4q..4q+3
    int c = cr / 3, r = cr - c * 3;
    float4 xv = *(const float4*)&x[(size_t)(b0 + b) * 21600 + c * 3600 + (3 * i + r) * 60 + (q << 2)];
    float vals[4] = {xv.x, xv.y, xv.z, xv.w};
#pragma unroll
    for (int m = 0; m < 4; ++m) {
      int col = (q << 2) + m;
      int j = col / 3, l = col - j * 3;
      sX[b * 1132 + j * 56 + l * 18 + c * 3 + r] = f2bf(vals[m]);
    }
  }
  // zero k=54,55 pads (uint write)
  for (int e = t; e < 320; e += 128) {
    int b = e / 20, j = e - b * 20;
    *(unsigned int*)&sX[b * 1132 + j * 56 + 54] = 0u;
  }

  const int jg = t >> 5, tid5 = t & 31;
  const int bg = tid5 & 3, cog = tid5 >> 2;

  for (int s = 0; s < 5; ++s) {
    __syncthreads();
    // stage W for 4 locs (bf16, already k-permuted/padded)
    const int loc0 = i * 20 + (s << 2);
    for (int e = t; e < 960; e += 128) {
      int wj = e / 240, r = e - wj * 240;
      *(uint4*)&sW[wj * 1928 + (r << 3)] =
          *(const uint4*)&W0p[(size_t)(loc0 + wj) * 1920 + (r << 3)];
    }
    __syncthreads();

    const int j = (s << 2) + jg;
    float acc[4][4] = {};
    for (int k4 = 0; k4 < 14; ++k4) {
      float wf[4][4];
#pragma unroll
      for (int uc = 0; uc < 4; ++uc) {
        ushort4 wv = *(const ushort4*)&sW[jg * 1928 + (cog * 4 + uc) * 60 + (k4 << 2)];
        wf[uc][0] = bf2f(wv.x); wf[uc][1] = bf2f(wv.y);
        wf[uc][2] = bf2f(wv.z); wf[uc][3] = bf2f(wv.w);
      }
#pragma unroll
      for (int rb = 0; rb < 4; ++rb) {
        ushort4 xv = *(const ushort4*)&sX[(bg * 4 + rb) * 1132 + j * 56 + (k4 << 2)];
        float xf0 = bf2f(xv.x), xf1 = bf2f(xv.y), xf2 = bf2f(xv.z), xf3 = bf2f(xv.w);
#pragma unroll
        for (int uc = 0; uc < 4; ++uc) {
          acc[rb][uc] = fmaf(xf0, wf[uc][0], acc[rb][uc]);
          acc[rb][uc] = fmaf(xf1, wf[uc][1], acc[rb][uc]);
          acc[rb][uc] = fmaf(xf2, wf[uc][2], acc[rb][uc]);
          acc[rb][uc] = fmaf(xf3, wf[uc][3], acc[rb][uc]);
        }
      }
    }
    // epilogue: bias + tanh + bf16 store (64B-contiguous chunks per (b,j))
    const int loc = i * 20 + j;
    const float4 bias = *(const float4*)&B0[loc * 32 + (cog << 2)];
    const float bb[4] = {bias.x, bias.y, bias.z, bias.w};
    const int o_off = (((i >> 1) * 10 + (j >> 1)) << 7) + (((i & 1) * 2 + (j & 1)) << 5) + (cog << 2);
#pragma unroll
    for (int rb = 0; rb < 4; ++rb) {
      int b = b0 + bg * 4 + rb;
      ushort4 q;
      q.x = f2bf(ftanh(acc[rb][0] + bb[0]));
      q.y = f2bf(ftanh(acc[rb][1] + bb[1]));
      q.z = f2bf(ftanh(acc[rb][2] + bb[2]));
      q.w = f2bf(ftanh(acc[rb][3] + bb[3]));
      *(ushort4*)&h0[(size_t)b * 12800 + o_off] = q;
    }
  }
}

// ---------- layer 1: 100 GEMMs [4096x128]*[128x64], tanh, bf16 out ----------
// h1 layout: [b][loc2(2x2)][kl5(5x5)][c(64)]
// block 128 thr; grid (32 batch-tiles of 128, 100 locs)
__global__ __launch_bounds__(128) void k_l1(const unsigned short* __restrict__ h0,
                                            const float* __restrict__ W1p,
                                            const float* __restrict__ B1,
                                            unsigned short* __restrict__ h1) {
  const int t   = threadIdx.x;
  const int b0  = blockIdx.x << 7;
  const int loc = blockIdx.y;
  const int i = loc / 10, j = loc - (loc / 10) * 10;

  __shared__ __align__(16) unsigned short sA[128 * 136];  // bf16, stride 136 (272B = 17*16)
  __shared__ __align__(16) float          sW[64 * 132];   // fp32, stride 132 (528B = 33*16)
  __shared__ float sB[64];

  for (int e = t; e < 2048; e += 128) {       // A: 128 rows x 16 uint4
    int b = e >> 4, c16 = e & 15;
    *(uint4*)&sA[b * 136 + (c16 << 3)] =
        *(const uint4*)&h0[(size_t)(b0 + b) * 12800 + (loc << 7) + (c16 << 3)];
  }
  for (int e = t; e < 2048; e += 128) {       // W: 64 rows x 32 float4
    int o = e >> 5, c4 = e & 31;
    *(float4*)&sW[o * 132 + (c4 << 2)] =
        *(const float4*)&W1p[(size_t)((loc * 64 + o) * 128) + (c4 << 2)];
  }
  if (t < 64) sB[t] = B1[(loc << 6) + t];
  __syncthreads();

  const int bl = t & 15;     // b = bl + 16r
  const int og = t >> 4;     // o = og + 8u (strided to dodge bank conflicts)
  float acc[8][8] = {};
#pragma unroll 2
  for (int kk = 0; kk < 128; kk += 4) {
    float4 wv[8];
#pragma unroll
    for (int u = 0; u < 8; ++u) wv[u] = *(const float4*)&sW[(og + (u << 3)) * 132 + kk];
#pragma unroll
    for (int r = 0; r < 8; ++r) {
      ushort4 av = *(const ushort4*)&sA[(bl + (r << 4)) * 136 + kk];
      float ax = bf2f(av.x), ay = bf2f(av.y), az = bf2f(av.z), aw = bf2f(av.w);
#pragma unroll
      for (int u = 0; u < 8; ++u) {
        acc[r][u] = fmaf(ax, wv[u].x, acc[r][u]);
        acc[r][u] = fmaf(ay, wv[u].y, acc[r][u]);
        acc[r][u] = fmaf(az, wv[u].z, acc[r][u]);
        acc[r][u] = fmaf(aw, wv[u].w, acc[r][u]);
      }
    }
  }
  __syncthreads();
  // restage through LDS (reuse sA) so global stores are 16B-coalesced
  unsigned short* sOut = sA;   // [128][72], 144B rows (9*16)
#pragma unroll
  for (int r = 0; r < 8; ++r) {
    int b = bl + (r << 4);
#pragma unroll
    for (int u = 0; u < 8; ++u) {
      int o = og + (u << 3);
      sOut[b * 72 + o] = f2bf(ftanh(acc[r][u] + sB[o]));
    }
  }
  __syncthreads();
  const int loc2 = (i / 5) * 2 + (j / 5);
  const int kl5  = (i % 5) * 5 + (j % 5);
  const int o_off1 = loc2 * 1600 + (kl5 << 6);
  for (int e = t; e < 1024; e += 128) {
    int b = e >> 3, c8 = e & 7;
    *(uint4*)&h1[(size_t)(b0 + b) * 6400 + o_off1 + (c8 << 3)] =
        *(const uint4*)&sOut[b * 72 + (c8 << 3)];
  }
}

// ---------- layer 2: 4 GEMMs [4096x1600]*[1600x128], K-split x4, fp32 partials ----------
// block 256 thr; grid (32 batch-tiles of 128, 4 k-splits, 4 locs)
__global__ __launch_bounds__(256) void k_l2(const unsigned short* __restrict__ h1,
                                            const float* __restrict__ W2p,
                                            float* __restrict__ h2p) {
  const int t   = threadIdx.x;
  const int b0  = blockIdx.x << 7;
  const int ks  = blockIdx.y;
  const int loc = blockIdx.z;

  __shared__ __align__(16) unsigned short sA[128 * 88];   // bf16, 176B rows
  __shared__ __align__(16) float          sW[128 * 84];   // fp32, 336B rows

  const int bl = t & 15;     // b = bl + 16r
  const int og = t >> 4;     // o = og + 16u
  float acc[8][8] = {};

  for (int kt = 0; kt < 5; ++kt) {
    const int f0 = ks * 400 + kt * 80;
    __syncthreads();
    for (int e = t; e < 1280; e += 256) {      // A: 128 rows x 10 uint4
      int b = e / 10, c = e - b * 10;
      *(uint4*)&sA[b * 88 + (c << 3)] =
          *(const uint4*)&h1[(size_t)(b0 + b) * 6400 + loc * 1600 + f0 + (c << 3)];
    }
    for (int e = t; e < 2560; e += 256) {      // W: 128 rows x 20 float4
      int o = e / 20, c = e - o * 20;
      *(float4*)&sW[o * 84 + (c << 2)] =
          *(const float4*)&W2p[(size_t)(loc * 128 + o) * 1600 + f0 + (c << 2)];
    }
    __syncthreads();
#pragma unroll 2
    for (int kk = 0; kk < 80; kk += 4) {
      float4 wv[8];
#pragma unroll
      for (int u = 0; u < 8; ++u) wv[u] = *(const float4*)&sW[(og + (u << 4)) * 84 + kk];
#pragma unroll
      for (int r = 0; r < 8; ++r) {
        ushort4 av = *(const ushort4*)&sA[(bl + (r << 4)) * 88 + kk];
        float ax = bf2f(av.x), ay = bf2f(av.y), az = bf2f(av.z), aw = bf2f(av.w);
#pragma unroll
        for (int u = 0; u < 8; ++u) {
          acc[r][u] = fmaf(ax, wv[u].x, acc[r][u]);
          acc[r][u] = fmaf(ay, wv[u].y, acc[r][u]);
          acc[r][u] = fmaf(az, wv[u].z, acc[r][u]);
          acc[r][u] = fmaf(aw, wv[u].w, acc[r][u]);
        }
      }
    }
  }
  // partials: [ks*4+loc][b][o]
  const size_t pbase = (size_t)(ks * 4 + loc) * 4096 * 128;
#pragma unroll
  for (int r = 0; r < 8; ++r) {
    int b = b0 + bl + (r << 4);
#pragma unroll
    for (int u = 0; u < 8; ++u)
      h2p[pbase + (size_t)b * 128 + og + (u << 4)] = acc[r][u];
  }
}

// ---------- reduce k-splits + bias + tanh -> h2[b][o*4+loc] ----------
__global__ __launch_bounds__(256) void k_l2red(const float* __restrict__ h2p,
                                               const float* __restrict__ B2,
                                               float* __restrict__ h2) {
  int idx = blockIdx.x * 256 + threadIdx.x;   // 4096*128
  int b = idx >> 7, o = idx & 127;
  float s0 = 0.f, s1 = 0.f, s2 = 0.f, s3 = 0.f;
  const size_t P = (size_t)4096 * 128;
#pragma unroll
  for (int ks = 0; ks < 4; ++ks) {
    size_t base = (size_t)(ks * 4) * P + (size_t)b * 128 + o;
    s0 += h2p[base];
    s1 += h2p[base + P];
    s2 += h2p[base + 2 * P];
    s3 += h2p[base + 3 * P];
  }
  float4 v;
  v.x = ftanh(s0 + B2[o]);
  v.y = ftanh(s1 + B2[128 + o]);
  v.z = ftanh(s2 + B2[256 + o]);
  v.w = ftanh(s3 + B2[384 + o]);
  *(float4*)&h2[(size_t)b * 512 + (o << 2)] = v;
}

// ---------- classifier + softmax: one wave per sample ----------
__global__ __launch_bounds__(256) void k_cls(const float* __restrict__ h2,
                                             const float* __restrict__ info,
                                             const float* __restrict__ Wc,
                                             const float* __restrict__ bc,
                                             float* __restrict__ out) {
  const int l = threadIdx.x & 63;
  const int b = blockIdx.x * 4 + (threadIdx.x >> 6);
  const float* hrow = h2 + (size_t)b * 512;
  float p0 = 0.f, p1 = 0.f;
#pragma unroll
  for (int f = 0; f < 512; f += 64) {
    float h = hrow[f + l];
    p0 = fmaf(h, Wc[2 * (f + l)], p0);
    p1 = fmaf(h, Wc[2 * (f + l) + 1], p1);
  }
#pragma unroll
  for (int m = 32; m; m >>= 1) {
    p0 += __shfl_xor(p0, m, 64);
    p1 += __shfl_xor(p1, m, 64);
  }
  if (l == 0) {
    float i0 = info[2 * b], i1 = info[2 * b + 1];
    float l0 = p0 + i0 * Wc[1024] + i1 * Wc[1026] + bc[0];
    float l1 = p1 + i0 * Wc[1025] + i1 * Wc[1027] + bc[1];
    float mx = fmaxf(l0, l1);
    float e0 = __expf(l0 - mx), e1 = __expf(l1 - mx);
    float inv = 1.f / (e0 + e1);
    out[2 * b]     = e0 * inv;
    out[2 * b + 1] = e1 * inv;
  }
}

extern "C" void kernel_launch(void* const* d_in, const int* in_sizes, int n_in,
                              void* d_out, int out_size, void* d_ws, size_t ws_size,
                              hipStream_t stream) {
  const float* x    = (const float*)d_in[0];
  const float* info = (const float*)d_in[1];
  const float* W0   = (const float*)d_in[2];
  const float* B0   = (const float*)d_in[3];
  const float* W1   = (const float*)d_in[4];
  const float* B1   = (const float*)d_in[5];
  const float* W2   = (const float*)d_in[6];
  const float* B2   = (const float*)d_in[7];
  const float* Wc   = (const float*)d_in[8];
  const float* bc   = (const float*)d_in[9];
  float* out = (float*)d_out;

  // ws layout (172.2 MB total):
  //   [0, 104857600)           h0 bf16 [4096][12800]   (dead after k_l1 -> reused by h2p)
  //   [0, 33554432)            h2p fp32 [16][4096][128] (aliases h0, written in k_l2)
  //   [104857600, +52428800)   h1 bf16 [4096][6400]
  //   [157286400, +8388608)    h2 fp32 [4096][512]; W0p bf16 (1.54MB) aliases its start
  //                            (W0p dead after k_l0; h2 written by k_l2red afterwards)
  //   [165675008, +3276800)    W1p fp32
  //   [168951808, +3276800)    W2p fp32
  char* ws = (char*)d_ws;
  unsigned short* h0  = (unsigned short*)ws;
  float*          h2p = (float*)ws;
  unsigned short* h1  = (unsigned short*)(ws + 104857600);
  float*          h2  = (float*)(ws + 104857600 + 52428800);
  unsigned short* W0p = (unsigned short*)(ws + 104857600 + 52428800);  // alias over h2
  float*          W1p = (float*)(ws + 104857600 + 52428800 + 8388608);
  float*          W2p = (float*)(ws + 104857600 + 52428800 + 8388608 + 3276800);

  k_permute<<<dim3(9400),       dim3(256), 0, stream>>>(W0, W1, W2, W0p, W1p, W2p);
  k_l0     <<<dim3(256, 20),    dim3(128), 0, stream>>>(x, W0p, B0, h0);
  k_l1     <<<dim3(32, 100),    dim3(128), 0, stream>>>(h0, W1p, B1, h1);
  k_l2     <<<dim3(32, 4, 4),   dim3(256), 0, stream>>>(h1, W2p, h2p);
  k_l2red  <<<dim3(2048),       dim3(256), 0, stream>>>(h2p, B2, h2);
  k_cls    <<<dim3(1024),       dim3(256), 0, stream>>>(h2, info, Wc, bc, out);
}

// Round 3
// 648.511 us; speedup vs baseline: 1.8791x; 1.8791x over previous
//
#include <hip/hip_runtime.h>

typedef short short8 __attribute__((ext_vector_type(8)));
typedef float floatx4 __attribute__((ext_vector_type(4)));

// ---------- helpers ----------
__device__ __forceinline__ float bf2f(unsigned short u) {
  union { unsigned int i; float f; } v; v.i = ((unsigned int)u) << 16; return v.f;
}
__device__ __forceinline__ unsigned short f2bf(float f) {
  union { float f; unsigned int i; } v; v.f = f;
  return (unsigned short)((v.i + 0x7fffu + ((v.i >> 16) & 1u)) >> 16);
}
__device__ __forceinline__ float ftanh(float x) {
  float e = __expf(2.f * x);
  return 1.f - 2.f / (e + 1.f);
}

// ---------- weight permutation into MFMA B-fragment order ----------
// Fragment for (gemm-tile): 64 lanes x 8 bf16; lane: n = lane&15, k = (lane>>4)*8 + e.
// W0f: frag id = (loc*2 + nt)*2 + ks          (400 locs, N=32 -> 2 nt, K=64 -> 2 ks)
//      k-order: kk = l*18 + (c*3 + r), kk>=54 -> 0
// W1f: frag id = (loc*4 + nt)*4 + ks          (100 locs, N=64 -> 4 nt, K=128 -> 4 ks)
//      k-order: kk = kl*32 + c   (kl = di*2+dj over L0 locs, c = L0 cout)
// W2f: frag id = ((loc*8 + nt)*50 + ks)       (4 locs, N=128 -> 8 nt, K=1600 -> 50 ks)
//      k-order: kk = kl5*64 + c  (kl5 = di*5+dj over L1 locs, c = L1 cout)
__global__ __launch_bounds__(256) void k_permute(const float* __restrict__ W0,
                                                 const float* __restrict__ W1,
                                                 const float* __restrict__ W2,
                                                 unsigned short* __restrict__ W0f,
                                                 unsigned short* __restrict__ W1f,
                                                 unsigned short* __restrict__ W2f) {
  int idx = blockIdx.x * 256 + threadIdx.x;      // 3 * 819200
  int sec = idx / 819200;
  int q = idx - sec * 819200;
  int frag = q >> 9, li = q & 511;
  int lane = li >> 3, e = li & 7;
  int n = lane & 15, quad = lane >> 4;
  if (sec == 0) {
    int loc = frag >> 2, nt = (frag >> 1) & 1, ks = frag & 1;
    int kk = (ks << 5) + (quad << 3) + e;
    int co = (nt << 4) + n;
    unsigned short v = 0;
    if (kk < 54) {
      int l = kk / 18, cr = kk - l * 18;
      v = f2bf(W0[loc * 1728 + co * 54 + cr * 3 + l]);
    }
    W0f[q] = v;
  } else if (sec == 1) {
    int loc = frag >> 4, nt = (frag >> 2) & 3, ks = frag & 3;
    int kk = (ks << 5) + (quad << 3) + e;
    int kl = kk >> 5, c = kk & 31, co = (nt << 4) + n;
    W1f[q] = f2bf(W1[(size_t)loc * 8192 + (co << 7) + (c << 2) + kl]);
  } else {
    int g = frag / 50, ks = frag - g * 50;
    int loc = g >> 3, nt = g & 7;
    int kk = (ks << 5) + (quad << 3) + e;
    int kl5 = kk >> 6, c = kk & 63, co = (nt << 4) + n;
    W2f[q] = f2bf(W2[(size_t)loc * 204800 + co * 1600 + c * 25 + kl5]);
  }
}

// ---------- layer 0: stage x -> LDS (A-frag k-order), MFMA per j ----------
// grid (256 b-tiles of 16, 20 i-stripes), block 256 (4 waves; wave w owns j = 5w..5w+4)
// sX bf16 [16 b][20 j][k 56], b-pitch 1128 us (2256 B: /16 = 141 odd -> chunk classes spread)
// h0: [b][loc1(10x10)][kl(2x2)][c32]
__global__ __launch_bounds__(256, 4) void k_l0(const float* __restrict__ x,
                                               const short8* __restrict__ W0f,
                                               const float* __restrict__ B0,
                                               unsigned short* __restrict__ h0) {
  const int t = threadIdx.x;
  const int b0 = blockIdx.x << 4;
  const int i = blockIdx.y;
  __shared__ __align__(16) unsigned short sX[16 * 1128];   // 36096 B

  for (int e = t; e < 4320; e += 256) {
    int b = e / 270, rem = e - b * 270;
    int cr = rem / 15, q = rem - cr * 15;
    float4 xv = *(const float4*)&x[(size_t)(b0 + b) * 21600 + (cr / 3) * 3600 +
                                   (3 * i + (cr % 3)) * 60 + (q << 2)];
    float vals[4] = {xv.x, xv.y, xv.z, xv.w};
#pragma unroll
    for (int m = 0; m < 4; ++m) {
      int col = (q << 2) + m;
      int j = col / 3, l = col - j * 3;
      sX[b * 1128 + j * 56 + l * 18 + cr] = f2bf(vals[m]);
    }
  }
  for (int e = t; e < 320; e += 256) {   // zero k = 54,55
    int b = e / 20, j = e - b * 20;
    *(unsigned int*)&sX[b * 1128 + j * 56 + 54] = 0u;
  }
  __syncthreads();

  const int lane = t & 63, w = t >> 6;
  const int n16 = lane & 15, quad = lane >> 4;
  const floatx4 z = {0.f, 0.f, 0.f, 0.f};

  for (int jj = 0; jj < 5; ++jj) {
    const int j = w * 5 + jj;
    const int loc = i * 20 + j;
    short8 a0 = *(const short8*)&sX[n16 * 1128 + j * 56 + (quad << 3)];
    short8 a1 = {};
    if (quad < 3) a1 = *(const short8*)&sX[n16 * 1128 + j * 56 + 32 + (quad << 3)];

    short8 b00 = W0f[(((loc << 1) + 0) << 1) * 64 + 0 * 64 + lane];
    short8 b01 = W0f[((((loc << 1) + 0) << 1) + 1) * 64 + lane];
    short8 b10 = W0f[((((loc << 1) + 1) << 1) + 0) * 64 + lane];
    short8 b11 = W0f[((((loc << 1) + 1) << 1) + 1) * 64 + lane];

    floatx4 acc0 = z, acc1 = z;
    acc0 = __builtin_amdgcn_mfma_f32_16x16x32_bf16(a0, b00, acc0, 0, 0, 0);
    acc0 = __builtin_amdgcn_mfma_f32_16x16x32_bf16(a1, b01, acc0, 0, 0, 0);
    acc1 = __builtin_amdgcn_mfma_f32_16x16x32_bf16(a0, b10, acc1, 0, 0, 0);
    acc1 = __builtin_amdgcn_mfma_f32_16x16x32_bf16(a1, b11, acc1, 0, 0, 0);

    const int o_off = (((i >> 1) * 10 + (j >> 1)) << 7) + (((i & 1) * 2 + (j & 1)) << 5);
    float bias0 = B0[loc * 32 + n16];
    float bias1 = B0[loc * 32 + 16 + n16];
#pragma unroll
    for (int reg = 0; reg < 4; ++reg) {
      int bb = b0 + (quad << 2) + reg;
      h0[(size_t)bb * 12800 + o_off + n16]      = f2bf(ftanh(acc0[reg] + bias0));
      h0[(size_t)bb * 12800 + o_off + 16 + n16] = f2bf(ftanh(acc1[reg] + bias1));
    }
  }
}

// ---------- layer 1: pure-MFMA, no LDS. grid (64 b-tiles of 64, 100 locs), 4 waves ----------
__global__ __launch_bounds__(256, 6) void k_l1(const unsigned short* __restrict__ h0,
                                               const short8* __restrict__ W1f,
                                               const float* __restrict__ B1,
                                               unsigned short* __restrict__ h1) {
  const int t = threadIdx.x, lane = t & 63, w = t >> 6;
  const int loc = blockIdx.y;
  const int i = loc / 10, j = loc - i * 10;
  const int b0 = (blockIdx.x << 6) + (w << 4);
  const int n16 = lane & 15, quad = lane >> 4;

  short8 a[4];
#pragma unroll
  for (int ks = 0; ks < 4; ++ks)
    a[ks] = *(const short8*)&h0[(size_t)(b0 + n16) * 12800 + (loc << 7) + (ks << 5) + (quad << 3)];

  const floatx4 z = {0.f, 0.f, 0.f, 0.f};
  floatx4 acc[4] = {z, z, z, z};
#pragma unroll
  for (int ks = 0; ks < 4; ++ks)
#pragma unroll
    for (int nt = 0; nt < 4; ++nt)
      acc[nt] = __builtin_amdgcn_mfma_f32_16x16x32_bf16(
          a[ks], W1f[(((loc << 2) + nt) << 2) * 64 + ks * 64 + lane], acc[nt], 0, 0, 0);

  const int loc2 = (i / 5) * 2 + (j / 5);
  const int kl5 = (i % 5) * 5 + (j % 5);
  const int obase = loc2 * 1600 + (kl5 << 6);
#pragma unroll
  for (int nt = 0; nt < 4; ++nt) {
    int co = (nt << 4) + n16;
    float bias = B1[(loc << 6) + co];
#pragma unroll
    for (int reg = 0; reg < 4; ++reg) {
      int bb = b0 + (quad << 2) + reg;
      h1[(size_t)bb * 6400 + obase + co] = f2bf(ftanh(acc[nt][reg] + bias));
    }
  }
}

// ---------- layer 2: pure-MFMA. grid (64 b-tiles of 64, 2 n-halves, 4 locs), 4 waves ----------
__global__ __launch_bounds__(256, 4) void k_l2(const unsigned short* __restrict__ h1,
                                               const short8* __restrict__ W2f,
                                               const float* __restrict__ B2,
                                               float* __restrict__ h2) {
  const int t = threadIdx.x, lane = t & 63, w = t >> 6;
  const int nh = blockIdx.y;
  const int loc = blockIdx.z;
  const int b0 = (blockIdx.x << 6) + (w << 4);
  const int n16 = lane & 15, quad = lane >> 4;

  const floatx4 z = {0.f, 0.f, 0.f, 0.f};
  floatx4 acc[4] = {z, z, z, z};
  const unsigned short* arow = h1 + (size_t)(b0 + n16) * 6400 + loc * 1600 + (quad << 3);
  const short8* wbase = W2f + (size_t)(((loc << 3) + (nh << 2)) * 50) * 64 + lane;

  for (int ks = 0; ks < 50; ++ks) {
    short8 a = *(const short8*)&arow[ks << 5];
#pragma unroll
    for (int nt4 = 0; nt4 < 4; ++nt4)
      acc[nt4] = __builtin_amdgcn_mfma_f32_16x16x32_bf16(
          a, wbase[(nt4 * 50 + ks) * 64], acc[nt4], 0, 0, 0);
  }

#pragma unroll
  for (int nt4 = 0; nt4 < 4; ++nt4) {
    int co = (((nh << 2) + nt4) << 4) + n16;
    float bias = B2[(loc << 7) + co];
#pragma unroll
    for (int reg = 0; reg < 4; ++reg) {
      int bb = b0 + (quad << 2) + reg;
      h2[(size_t)bb * 512 + (co << 2) + loc] = ftanh(acc[nt4][reg] + bias);
    }
  }
}

// ---------- classifier + softmax: one wave per sample ----------
__global__ __launch_bounds__(256) void k_cls(const float* __restrict__ h2,
                                             const float* __restrict__ info,
                                             const float* __restrict__ Wc,
                                             const float* __restrict__ bc,
                                             float* __restrict__ out) {
  const int l = threadIdx.x & 63;
  const int b = blockIdx.x * 4 + (threadIdx.x >> 6);
  const float* hrow = h2 + (size_t)b * 512;
  float p0 = 0.f, p1 = 0.f;
#pragma unroll
  for (int f = 0; f < 512; f += 64) {
    float h = hrow[f + l];
    p0 = fmaf(h, Wc[2 * (f + l)], p0);
    p1 = fmaf(h, Wc[2 * (f + l) + 1], p1);
  }
#pragma unroll
  for (int m = 32; m; m >>= 1) {
    p0 += __shfl_xor(p0, m, 64);
    p1 += __shfl_xor(p1, m, 64);
  }
  if (l == 0) {
    float i0 = info[2 * b], i1 = info[2 * b + 1];
    float l0 = p0 + i0 * Wc[1024] + i1 * Wc[1026] + bc[0];
    float l1 = p1 + i0 * Wc[1025] + i1 * Wc[1027] + bc[1];
    float mx = fmaxf(l0, l1);
    float e0 = __expf(l0 - mx), e1 = __expf(l1 - mx);
    float inv = 1.f / (e0 + e1);
    out[2 * b]     = e0 * inv;
    out[2 * b + 1] = e1 * inv;
  }
}

extern "C" void kernel_launch(void* const* d_in, const int* in_sizes, int n_in,
                              void* d_out, int out_size, void* d_ws, size_t ws_size,
                              hipStream_t stream) {
  const float* x    = (const float*)d_in[0];
  const float* info = (const float*)d_in[1];
  const float* W0   = (const float*)d_in[2];
  const float* B0   = (const float*)d_in[3];
  const float* W1   = (const float*)d_in[4];
  const float* B1   = (const float*)d_in[5];
  const float* W2   = (const float*)d_in[6];
  const float* B2   = (const float*)d_in[7];
  const float* Wc   = (const float*)d_in[8];
  const float* bc   = (const float*)d_in[9];
  float* out = (float*)d_out;

  // ws layout (170.6 MB):
  //   [0, 104857600)           h0 bf16 [4096][12800]
  //   [104857600, +52428800)   h1 bf16 [4096][6400]
  //   [157286400, +8388608)    h2 fp32 [4096][512]
  //   [165675008, +1638400)    W0f bf16 frags
  //   [167313408, +1638400)    W1f bf16 frags
  //   [168951808, +1638400)    W2f bf16 frags
  char* ws = (char*)d_ws;
  unsigned short* h0  = (unsigned short*)ws;
  unsigned short* h1  = (unsigned short*)(ws + 104857600);
  float*          h2  = (float*)(ws + 157286400);
  unsigned short* W0f = (unsigned short*)(ws + 165675008);
  unsigned short* W1f = (unsigned short*)(ws + 167313408);
  unsigned short* W2f = (unsigned short*)(ws + 168951808);

  k_permute<<<dim3(9600),     dim3(256), 0, stream>>>(W0, W1, W2, W0f, W1f, W2f);
  k_l0     <<<dim3(256, 20),  dim3(256), 0, stream>>>(x, (const short8*)W0f, B0, h0);
  k_l1     <<<dim3(64, 100),  dim3(256), 0, stream>>>(h0, (const short8*)W1f, B1, h1);
  k_l2     <<<dim3(64, 2, 4), dim3(256), 0, stream>>>(h1, (const short8*)W2f, B2, h2);
  k_cls    <<<dim3(1024),     dim3(256), 0, stream>>>(h2, info, Wc, bc, out);
}

// Round 4
// 603.324 us; speedup vs baseline: 2.0198x; 1.0749x over previous
//
#include <hip/hip_runtime.h>

typedef short short8 __attribute__((ext_vector_type(8)));
typedef float floatx4 __attribute__((ext_vector_type(4)));

// ---------- helpers ----------
__device__ __forceinline__ unsigned short f2bf(float f) {
  union { float f; unsigned int i; } v; v.f = f;
  return (unsigned short)((v.i + 0x7fffu + ((v.i >> 16) & 1u)) >> 16);
}
__device__ __forceinline__ float ftanh(float x) {
  float e = __expf(2.f * x);
  return 1.f - 2.f / (e + 1.f);
}

// ---------- weight permutation into MFMA B-fragment order ----------
// Fragment: 64 lanes x 8 bf16; lane: n = lane&15, k = (lane>>4)*8 + e.
// W0f: frag id = (loc*2 + nt)*2 + ks   (400 locs, N=32 -> 2 nt, K=64 -> 2 ks)
//      k-order kk = NATURAL W0 order c*9 + r*3 + l  (kk>=54 -> 0)
// W1f: frag id = (loc*4 + nt)*4 + ks   (100 locs, N=64 -> 4 nt, K=128 -> 4 ks)
//      k-order: kk = kl*32 + c   (kl = di*2+dj over L0 sub-locs, c = L0 cout)
// W2f: frag id = (loc*8 + nt)*50 + ks  (4 locs, N=128 -> 8 nt, K=1600 -> 50 ks)
//      k-order: kk = kl5*64 + c  (kl5 = di*5+dj over L1 sub-locs, c = L1 cout)
__global__ __launch_bounds__(256) void k_permute(const float* __restrict__ W0,
                                                 const float* __restrict__ W1,
                                                 const float* __restrict__ W2,
                                                 unsigned short* __restrict__ W0f,
                                                 unsigned short* __restrict__ W1f,
                                                 unsigned short* __restrict__ W2f) {
  int idx = blockIdx.x * 256 + threadIdx.x;      // 3 * 819200
  int sec = idx / 819200;
  int q = idx - sec * 819200;
  int frag = q >> 9, li = q & 511;
  int lane = li >> 3, e = li & 7;
  int n = lane & 15, quad = lane >> 4;
  if (sec == 0) {
    int loc = frag >> 2, nt = (frag >> 1) & 1, ks = frag & 1;
    int kk = (ks << 5) + (quad << 3) + e;
    int co = (nt << 4) + n;
    unsigned short v = 0;
    if (kk < 54) v = f2bf(W0[loc * 1728 + co * 54 + kk]);
    W0f[q] = v;
  } else if (sec == 1) {
    int loc = frag >> 4, nt = (frag >> 2) & 3, ks = frag & 3;
    int kk = (ks << 5) + (quad << 3) + e;
    int kl = kk >> 5, c = kk & 31, co = (nt << 4) + n;
    W1f[q] = f2bf(W1[(size_t)loc * 8192 + (co << 7) + (c << 2) + kl]);
  } else {
    int g = frag / 50, ks = frag - g * 50;
    int loc = g >> 3, nt = g & 7;
    int kk = (ks << 5) + (quad << 3) + e;
    int kl5 = kk >> 6, c = kk & 63, co = (nt << 4) + n;
    W2f[q] = f2bf(W2[(size_t)loc * 204800 + co * 1600 + c * 25 + kl5]);
  }
}

// ---------- layer 0 v3: natural-k staging (vectorized LDS writes), MFMA per j ----------
// grid (256 b-tiles of 16, 20 i-stripes), block 320 (5 waves; wave w owns j = 4w..4w+3)
// sX bf16 [16 b][20 j][k 56] natural k-order (c*9+r*3+l), b-pitch 1128 elems.
// Staging: one thread per (b,j); 9 iterations x (6 scalar loads + 3 ds_write_b32).
// h0: [b][loc1(10x10)][kl(2x2)][c32]
__global__ __launch_bounds__(320, 5) void k_l0(const float* __restrict__ x,
                                               const short8* __restrict__ W0f,
                                               const float* __restrict__ B0,
                                               unsigned short* __restrict__ h0) {
  const int t = threadIdx.x;
  const int b0 = blockIdx.x << 4;
  const int i = blockIdx.y;
  __shared__ __align__(16) unsigned short sX[16 * 1128];   // 36096 B

  {
    const int b = t / 20, j = t - (t / 20) * 20;
    const float* xb = x + (size_t)(b0 + b) * 21600 + (3 * i) * 60 + 3 * j;
    unsigned short* dst = &sX[b * 1128 + j * 56];
    int c = 0, r = 0;
#pragma unroll
    for (int p = 0; p < 9; ++p) {
      const float* pa = xb + c * 3600 + r * 60;
      float a0 = pa[0], a1 = pa[1], a2 = pa[2];
      ++r; if (r == 3) { r = 0; ++c; }
      const float* pb = xb + c * 3600 + r * 60;
      float b0v = pb[0], b1v = pb[1], b2v = pb[2];
      ++r; if (r == 3) { r = 0; ++c; }
      unsigned int w0 = (unsigned int)f2bf(a0) | ((unsigned int)f2bf(a1) << 16);
      unsigned int w1 = (unsigned int)f2bf(a2) | ((unsigned int)f2bf(b0v) << 16);
      unsigned int w2 = (unsigned int)f2bf(b1v) | ((unsigned int)f2bf(b2v) << 16);
      *(unsigned int*)&dst[p * 6]     = w0;
      *(unsigned int*)&dst[p * 6 + 2] = w1;
      *(unsigned int*)&dst[p * 6 + 4] = w2;
    }
    *(unsigned int*)&dst[54] = 0u;   // pad k = 54,55
  }
  __syncthreads();

  const int lane = t & 63, w = t >> 6;
  const int n16 = lane & 15, quad = lane >> 4;
  const floatx4 z = {0.f, 0.f, 0.f, 0.f};

#pragma unroll
  for (int jj = 0; jj < 4; ++jj) {
    const int j = (w << 2) + jj;
    const int loc = i * 20 + j;
    short8 a0 = *(const short8*)&sX[n16 * 1128 + j * 56 + (quad << 3)];
    short8 a1 = {};
    if (quad < 3) a1 = *(const short8*)&sX[n16 * 1128 + j * 56 + 32 + (quad << 3)];

    short8 b00 = W0f[((loc << 2) + 0) * 64 + lane];
    short8 b01 = W0f[((loc << 2) + 1) * 64 + lane];
    short8 b10 = W0f[((loc << 2) + 2) * 64 + lane];
    short8 b11 = W0f[((loc << 2) + 3) * 64 + lane];

    floatx4 acc0 = z, acc1 = z;
    acc0 = __builtin_amdgcn_mfma_f32_16x16x32_bf16(a0, b00, acc0, 0, 0, 0);
    acc0 = __builtin_amdgcn_mfma_f32_16x16x32_bf16(a1, b01, acc0, 0, 0, 0);
    acc1 = __builtin_amdgcn_mfma_f32_16x16x32_bf16(a0, b10, acc1, 0, 0, 0);
    acc1 = __builtin_amdgcn_mfma_f32_16x16x32_bf16(a1, b11, acc1, 0, 0, 0);

    const int o_off = (((i >> 1) * 10 + (j >> 1)) << 7) + (((i & 1) * 2 + (j & 1)) << 5);
    float bias0 = B0[loc * 32 + n16];
    float bias1 = B0[loc * 32 + 16 + n16];
#pragma unroll
    for (int reg = 0; reg < 4; ++reg) {
      int bb = b0 + (quad << 2) + reg;
      h0[(size_t)bb * 12800 + o_off + n16]      = f2bf(ftanh(acc0[reg] + bias0));
      h0[(size_t)bb * 12800 + o_off + 16 + n16] = f2bf(ftanh(acc1[reg] + bias1));
    }
  }
}

// ---------- fused layers 1+2: per block = 16 samples x 1 output quadrant ----------
// Phase 1: 25 L1 GEMMs [16x128]*[128x64] -> tanh -> bf16 into LDS sH (W2 k-order).
// Phase 2: L2 GEMM [16x1600]*[1600x128] from LDS A-frags, tanh -> h2 fp32.
// grid (256 b-tiles, 4 quadrants), block 256 (4 waves).
// sH: [16 m][1600 k] bf16, pitch 1608 elems (3216 B) -> 51456 B, 2 blocks/CU.
__global__ __launch_bounds__(256, 2) void k_l12(const unsigned short* __restrict__ h0,
                                                const short8* __restrict__ W1f,
                                                const float* __restrict__ B1,
                                                const short8* __restrict__ W2f,
                                                const float* __restrict__ B2,
                                                float* __restrict__ h2) {
  const int t = threadIdx.x, lane = t & 63, w = t >> 6;
  const int n16 = lane & 15, quad = lane >> 4;
  const int b0 = blockIdx.x << 4;
  const int q = blockIdx.y;                  // quadrant = loc2 = I*2+J
  const int i0 = (q >> 1) * 5, j0 = (q & 1) * 5;

  __shared__ __align__(16) unsigned short sH[16 * 1608];   // 51456 B

  const floatx4 z = {0.f, 0.f, 0.f, 0.f};

  // ---- phase 1: L1 into LDS (wave w handles locs li = w, w+4, ...)
  for (int li = w; li < 25; li += 4) {
    const int di = li / 5, dj = li - di * 5;
    const int loc = (i0 + di) * 10 + (j0 + dj);

    short8 a[4];
#pragma unroll
    for (int ks = 0; ks < 4; ++ks)
      a[ks] = *(const short8*)&h0[(size_t)(b0 + n16) * 12800 + (loc << 7) + (ks << 5) + (quad << 3)];

    floatx4 acc[4] = {z, z, z, z};
#pragma unroll
    for (int ks = 0; ks < 4; ++ks)
#pragma unroll
      for (int nt = 0; nt < 4; ++nt)
        acc[nt] = __builtin_amdgcn_mfma_f32_16x16x32_bf16(
            a[ks], W1f[(((loc << 2) + nt) << 2) * 64 + ks * 64 + lane], acc[nt], 0, 0, 0);

    // write into sH: row = quad*4+reg (m), col = li*64 + nt*16 + n16 (W2 k-order)
#pragma unroll
    for (int nt = 0; nt < 4; ++nt) {
      float bias = B1[(loc << 6) + (nt << 4) + n16];
      int col = (li << 6) + (nt << 4) + n16;
#pragma unroll
      for (int reg = 0; reg < 4; ++reg)
        sH[((quad << 2) + reg) * 1608 + col] = f2bf(ftanh(acc[nt][reg] + bias));
    }
  }
  __syncthreads();

  // ---- phase 2: L2 from LDS; wave w owns nt = 2w, 2w+1
  floatx4 acc0 = z, acc1 = z;
  const short8* wb0 = W2f + (size_t)(((q << 3) + (w << 1)) * 50) * 64 + lane;
  const short8* wb1 = wb0 + (size_t)50 * 64;
  for (int ks = 0; ks < 50; ++ks) {
    short8 a = *(const short8*)&sH[n16 * 1608 + (ks << 5) + (quad << 3)];
    acc0 = __builtin_amdgcn_mfma_f32_16x16x32_bf16(a, wb0[ks * 64], acc0, 0, 0, 0);
    acc1 = __builtin_amdgcn_mfma_f32_16x16x32_bf16(a, wb1[ks * 64], acc1, 0, 0, 0);
  }

#pragma unroll
  for (int u = 0; u < 2; ++u) {
    const floatx4& ac = u ? acc1 : acc0;
    int co = (((w << 1) + u) << 4) + n16;
    float bias = B2[(q << 7) + co];
#pragma unroll
    for (int reg = 0; reg < 4; ++reg) {
      int bb = b0 + (quad << 2) + reg;
      h2[(size_t)bb * 512 + (co << 2) + q] = ftanh(ac[reg] + bias);
    }
  }
}

// ---------- classifier + softmax: one wave per sample ----------
__global__ __launch_bounds__(256) void k_cls(const float* __restrict__ h2,
                                             const float* __restrict__ info,
                                             const float* __restrict__ Wc,
                                             const float* __restrict__ bc,
                                             float* __restrict__ out) {
  const int l = threadIdx.x & 63;
  const int b = blockIdx.x * 4 + (threadIdx.x >> 6);
  const float* hrow = h2 + (size_t)b * 512;
  float p0 = 0.f, p1 = 0.f;
#pragma unroll
  for (int f = 0; f < 512; f += 64) {
    float h = hrow[f + l];
    p0 = fmaf(h, Wc[2 * (f + l)], p0);
    p1 = fmaf(h, Wc[2 * (f + l) + 1], p1);
  }
#pragma unroll
  for (int m = 32; m; m >>= 1) {
    p0 += __shfl_xor(p0, m, 64);
    p1 += __shfl_xor(p1, m, 64);
  }
  if (l == 0) {
    float i0 = info[2 * b], i1 = info[2 * b + 1];
    float l0 = p0 + i0 * Wc[1024] + i1 * Wc[1026] + bc[0];
    float l1 = p1 + i0 * Wc[1025] + i1 * Wc[1027] + bc[1];
    float mx = fmaxf(l0, l1);
    float e0 = __expf(l0 - mx), e1 = __expf(l1 - mx);
    float inv = 1.f / (e0 + e1);
    out[2 * b]     = e0 * inv;
    out[2 * b + 1] = e1 * inv;
  }
}

extern "C" void kernel_launch(void* const* d_in, const int* in_sizes, int n_in,
                              void* d_out, int out_size, void* d_ws, size_t ws_size,
                              hipStream_t stream) {
  const float* x    = (const float*)d_in[0];
  const float* info = (const float*)d_in[1];
  const float* W0   = (const float*)d_in[2];
  const float* B0   = (const float*)d_in[3];
  const float* W1   = (const float*)d_in[4];
  const float* B1   = (const float*)d_in[5];
  const float* W2   = (const float*)d_in[6];
  const float* B2   = (const float*)d_in[7];
  const float* Wc   = (const float*)d_in[8];
  const float* bc   = (const float*)d_in[9];
  float* out = (float*)d_out;

  // ws layout (118.1 MB):
  //   [0, 104857600)           h0 bf16 [4096][12800]
  //   [104857600, +8388608)    h2 fp32 [4096][512]
  //   [113246208, +1638400)    W0f bf16 frags
  //   [114884608, +1638400)    W1f bf16 frags
  //   [116523008, +1638400)    W2f bf16 frags
  char* ws = (char*)d_ws;
  unsigned short* h0  = (unsigned short*)ws;
  float*          h2  = (float*)(ws + 104857600);
  unsigned short* W0f = (unsigned short*)(ws + 113246208);
  unsigned short* W1f = (unsigned short*)(ws + 114884608);
  unsigned short* W2f = (unsigned short*)(ws + 116523008);

  k_permute<<<dim3(9600),    dim3(256), 0, stream>>>(W0, W1, W2, W0f, W1f, W2f);
  k_l0     <<<dim3(256, 20), dim3(320), 0, stream>>>(x, (const short8*)W0f, B0, h0);
  k_l12    <<<dim3(256, 4),  dim3(256), 0, stream>>>(h0, (const short8*)W1f, B1,
                                                     (const short8*)W2f, B2, h2);
  k_cls    <<<dim3(1024),    dim3(256), 0, stream>>>(h2, info, Wc, bc, out);
}